// Round 4
// baseline (515.749 us; speedup 1.0000x reference)
//
#include <hip/hip_runtime.h>
#include <stdint.h>

#define BATCH 65536
#define FDIM 512
#define HDIM 256
#define NC 10
#define NREP 16

typedef short short8 __attribute__((ext_vector_type(8)));
typedef float f32x4 __attribute__((ext_vector_type(4)));

// ---- workspace layout (bytes) ----
// Fragment-tiled layout: tile (I=row/16, C=k/32) is 1KB at (I*nC + C)*1024;
// slot l = (row&15) | (((k>>3)&3)<<4) holds 8 bf16 (k = (l>>4)*8 .. +7).
#define OFF_FC0T   ((size_t)0)                          // 32 J x 16 C tiles
#define OFF_FC1T   (OFF_FC0T + (size_t)512*512*2)
#define OFF_WT     (OFF_FC1T + (size_t)512*512*2)       // 16 J x 16 C tiles
#define OFF_XT     (OFF_WT   + (size_t)256*512*2)       // 4096 I x 16 C (64MB)
#define OFF_X4T    (OFF_XT   + (size_t)BATCH*512*2)     // 4096 I x 16 C (64MB)
#define OFF_ACC    (OFF_X4T  + (size_t)BATCH*512*2)
#define SCAL_SUMSQ 0
#define SCAL_CE    16
#define SCAL_ACC   32
#define SCAL_L1    48
#define SCAL_N     128
#define CNT_OFF    SCAL_N                 // NREP*16 floats
#define GSUM_OFF   (SCAL_N + NREP*16)     // NREP*5120 floats
#define ACC_FLOATS (GSUM_OFF + NREP*5120) // 82304 floats
#define OFF_W1T    (OFF_ACC + (size_t)ACC_FLOATS*4)     // 8 C-tiles x 1KB (w1 bf16, padded to 16 classes)

#define GLL(g,l) __builtin_amdgcn_global_load_lds((const __attribute__((address_space(1))) void*)(g), (__attribute__((address_space(3))) void*)(l), 16, 0, 0)

__device__ __forceinline__ unsigned short f2b(float f){
  unsigned u = __float_as_uint(f);
  u += 0x7FFFu + ((u >> 16) & 1u);
  return (unsigned short)(u >> 16);
}
__device__ __forceinline__ float b2f(unsigned short h){
  return __uint_as_float(((unsigned)h) << 16);
}
__device__ __forceinline__ unsigned pk2b(float f0, float f1){
  unsigned u0 = __float_as_uint(f0) + 0x8000u;
  unsigned u1 = __float_as_uint(f1) + 0x8000u;
  return __builtin_amdgcn_perm(u1, u0, 0x07060302u);
}

// ---- K0: setup — xcast (blocks 0..1023), weight prep (1024..1359), zero (1360..1440)
__global__ __launch_bounds__(256) void k_setup(
    const float* __restrict__ x,   const float* __restrict__ fc0,
    const float* __restrict__ fc1, const float* __restrict__ w,
    const float* __restrict__ w1,
    unsigned short* __restrict__ xT,   unsigned short* __restrict__ fc0T,
    unsigned short* __restrict__ fc1T, unsigned short* __restrict__ wT,
    unsigned short* __restrict__ w1T,  float* __restrict__ accb)
{
  int blk = blockIdx.x, t = threadIdx.x;
  if (blk < 1024){
    // x fp32 -> fragment-tiled bf16; one wave per I-tile
    int I = blk*4 + (t >> 6);
    int l = t & 63;
    int row = I*16 + (l & 15), q = l >> 4;
    const float* src = x + (size_t)row*FDIM + q*8;
    #pragma unroll
    for (int C = 0; C < 16; ++C){
      float4 v0 = *(const float4*)(src + C*32);
      float4 v1 = *(const float4*)(src + C*32 + 4);
      unsigned o[4];
      o[0] = pk2b(v0.x, v0.y); o[1] = pk2b(v0.z, v0.w);
      o[2] = pk2b(v1.x, v1.y); o[3] = pk2b(v1.z, v1.w);
      *(short8*)&xT[(((size_t)I*16 + C) << 9) + l*8] = *(short8*)o;
    }
    return;
  }
  if (blk < 1360){
    int i = (blk - 1024)*256 + t;
    float l1v = 0.f;
    if (i < 32768){                       // fc0 [k][512] -> tiled
      int n4 = i&15, m = (i>>4)&3, C = (i>>6)&15, J = i>>10;
      int n = J*16+n4, k8 = C*4+m;
      unsigned short o[8];
      #pragma unroll
      for (int j=0;j<8;++j){ float v = fc0[(size_t)(k8*8+j)*512 + n]; o[j]=f2b(v); l1v += fabsf(v); }
      *(short8*)&fc0T[(size_t)(J*16+C)*512 + (i&63)*8] = *(short8*)o;
    } else if (i < 65536){                // fc1
      int j0 = i - 32768;
      int n4 = j0&15, m = (j0>>4)&3, C = (j0>>6)&15, J = j0>>10;
      int n = J*16+n4, k8 = C*4+m;
      unsigned short o[8];
      #pragma unroll
      for (int j=0;j<8;++j){ float v = fc1[(size_t)(k8*8+j)*512 + n]; o[j]=f2b(v); l1v += fabsf(v); }
      *(short8*)&fc1T[(size_t)(J*16+C)*512 + (j0&63)*8] = *(short8*)o;
    } else if (i < 81920){                // w [k][256]
      int j0 = i - 65536;
      int n4 = j0&15, m = (j0>>4)&3, C = (j0>>6)&15, J = j0>>10;
      int n = J*16+n4, k8 = C*4+m;
      unsigned short o[8];
      #pragma unroll
      for (int j=0;j<8;++j){ float v = w[(size_t)(k8*8+j)*256 + n]; o[j]=f2b(v); l1v += fabsf(v); }
      *(short8*)&wT[(size_t)(J*16+C)*512 + (j0&63)*8] = *(short8*)o;
    } else if (i < 86016){                // w1 -> B-fragment tiles (16 classes padded), + L1
      int j0 = i - 81920;                 // 0..4095, one bf16 each
      int C = j0 >> 9, l = (j0 >> 3) & 63, e = j0 & 7;
      int n = l & 15, k = C*32 + (l>>4)*8 + e;
      float v = (n < NC) ? w1[k*NC + n] : 0.f;
      w1T[C*512 + l*8 + e] = f2b(v);
      if (n < NC) l1v = fabsf(v);
    }
    for (int off = 32; off; off >>= 1) l1v += __shfl_down(l1v, off);
    if ((t & 63) == 0 && l1v != 0.f)
      atomicAdd(&accb[SCAL_L1 + (blk & (NREP-1))], l1v);
    return;
  }
  {
    int base = (blk - 1360)*1024;
    #pragma unroll
    for (int j=0;j<4;++j){
      int idx = base + j*256 + t;
      if (idx < ACC_FLOATS) accb[idx] = 0.f;
    }
  }
}

// K1: dual GEMM x1=x@fc0, x2=relu(x@fc1); x4 = x + (1+sig(x1))*x2 -> tiled bf16.
// Fused: sumsq(x4), per-class column sums (csum), class counts (colblk==0).
__global__ __launch_bounds__(256) void k_gemm12(
    const unsigned short* __restrict__ xT,
    const unsigned short* __restrict__ fc0T,
    const unsigned short* __restrict__ fc1T,
    const int* __restrict__ y,
    unsigned short* __restrict__ x4T,
    float* __restrict__ scal, float* __restrict__ gcnt, float* __restrict__ gsum)
{
  __shared__ __align__(16) char lds[32768];
  unsigned short* As    = (unsigned short*)lds;           // 16 x 1KB tiles
  unsigned short* Bs0   = (unsigned short*)(lds + 16384); // 8 x 1KB
  unsigned short* Bs1   = (unsigned short*)(lds + 24576); // 8 x 1KB
  unsigned short* trans = (unsigned short*)(lds + 16384); // epilogue reuse, 16KB
  __shared__ float red[4];
  __shared__ float csLDS[NC*64];
  __shared__ int   ysS[128];
  __shared__ float cntS[NC];

  int blk = blockIdx.x;
  int xcd = blk & 7, s = blk >> 3;
  int rowblk = xcd*64 + (s >> 3);
  int colblk = s & 7;
  int rep = (blk ^ (blk >> 6)) & (NREP-1);

  int t = threadIdx.x;
  int wv = t >> 6, lane = t & 63, ln = lane & 15, quad = lane >> 4;
  int wr = wv >> 1, wc = wv & 1;

  if (t < 128) ysS[t] = y[rowblk*128 + t];
  if (t < NC) cntS[t] = 0.f;
  for (int i = t; i < NC*64; i += 256) csLDS[i] = 0.f;

  const f32x4 zv = {0.f,0.f,0.f,0.f};
  f32x4 acc1[4][2], acc2[4][2];
  #pragma unroll
  for (int rt=0;rt<4;++rt){ acc1[rt][0]=zv; acc1[rt][1]=zv; acc2[rt][0]=zv; acc2[rt][1]=zv; }

  const char* xb  = (const char*)xT;
  const char* b0b = (const char*)fc0T;
  const char* b1b = (const char*)fc1T;

  for (int kt = 0; kt < 8; ++kt){
    #pragma unroll
    for (int i = 0; i < 2; ++i)
      #pragma unroll
      for (int c = 0; c < 2; ++c){
        size_t Ig = (size_t)(rowblk*8 + wv*2 + i);
        GLL(xb + ((Ig*16 + kt*2 + c) << 10) + lane*16,
            (char*)As + (((wv*2+i)*2 + c) << 10));
      }
    {
      size_t Jg = (size_t)(colblk*4 + wv);
      const char* g0 = b0b + ((Jg*16 + kt*2) << 10) + lane*16;
      const char* g1 = b1b + ((Jg*16 + kt*2) << 10) + lane*16;
      GLL(g0,        (char*)Bs0 + ((wv*2+0) << 10));
      GLL(g0 + 1024, (char*)Bs0 + ((wv*2+1) << 10));
      GLL(g1,        (char*)Bs1 + ((wv*2+0) << 10));
      GLL(g1 + 1024, (char*)Bs1 + ((wv*2+1) << 10));
    }
    __syncthreads();
    #pragma unroll
    for (int c = 0; c < 2; ++c){
      short8 a[4];
      #pragma unroll
      for (int rt=0;rt<4;++rt)
        a[rt] = *(const short8*)&As[(((wr*4+rt)*2 + c) << 9) + lane*8];
      #pragma unroll
      for (int ct=0;ct<2;++ct){
        int jl = wc*2 + ct;
        short8 b0 = *(const short8*)&Bs0[((jl*2+c) << 9) + lane*8];
        #pragma unroll
        for (int rt=0;rt<4;++rt)
          acc1[rt][ct] = __builtin_amdgcn_mfma_f32_16x16x32_bf16(a[rt], b0, acc1[rt][ct], 0,0,0);
        short8 b1 = *(const short8*)&Bs1[((jl*2+c) << 9) + lane*8];
        #pragma unroll
        for (int rt=0;rt<4;++rt)
          acc2[rt][ct] = __builtin_amdgcn_mfma_f32_16x16x32_bf16(a[rt], b1, acc2[rt][ct], 0,0,0);
      }
    }
    __syncthreads();
  }

  // re-stage this block's own column-slice of x (bf16) for the residual
  #pragma unroll
  for (int i = 0; i < 2; ++i)
    #pragma unroll
    for (int c = 0; c < 2; ++c){
      size_t Ig = (size_t)(rowblk*8 + wv*2 + i);
      GLL(xb + ((Ig*16 + colblk*2 + c) << 10) + lane*16,
          (char*)As + (((wv*2+i)*2 + c) << 10));
    }
  if (colblk == 0 && t < 128) atomicAdd(&cntS[ysS[t]], 1.f);
  __syncthreads();

  float sumsq = 0.f;
  #pragma unroll
  for (int rt=0;rt<4;++rt){
    #pragma unroll
    for (int r=0;r<4;++r){
      int row_l = wr*64 + rt*16 + quad*4 + r;
      int cls = ysS[row_l];
      #pragma unroll
      for (int ct=0;ct<2;++ct){
        int col_l = wc*32 + ct*16 + ln;
        int slot_hi = (ct*2 + (ln>>3)) << 4;
        int addr = (((wr*4+rt)*2 + wc) << 9) + ((quad*4+r) | slot_hi)*8 + (ln & 7);
        float xv  = b2f(As[addr]);
        float x1v = acc1[rt][ct][r];
        float x2v = fmaxf(acc2[rt][ct][r], 0.f);
        float gate = 1.f + 1.f/(1.f + __expf(-x1v));
        float x4v = fmaf(gate, x2v, xv);
        unsigned short ub = f2b(x4v);
        float fq = b2f(ub);
        sumsq = fmaf(fq, fq, sumsq);
        trans[addr] = ub;                       // identical tiled position in x4
        atomicAdd(&csLDS[cls*64 + col_l], fq);  // per-class column sums
      }
    }
  }
  for (int off = 32; off; off >>= 1) sumsq += __shfl_down(sumsq, off);
  if (lane == 0) red[wv] = sumsq;
  __syncthreads();
  if (t == 0)
    atomicAdd(&scal[SCAL_SUMSQ + rep], red[0]+red[1]+red[2]+red[3]);
  // flush csum + counts, store x4 tile
  for (int i = t; i < NC*64; i += 256){
    int c = i >> 6, col = i & 63;
    atomicAdd(&gsum[(size_t)rep*5120 + c*512 + colblk*64 + col], csLDS[i]);
  }
  if (colblk == 0 && t < NC) atomicAdd(&gcnt[rep*16 + t], cntS[t]);
  {
    int lt = t >> 4;
    int I_local = lt >> 1, C_local = lt & 1;
    size_t gbase = ((size_t)(rowblk*8 + I_local)*16 + colblk*2 + C_local) << 9;
    int s0 = (t & 15)*32;
    #pragma unroll
    for (int j=0;j<4;++j)
      *(short8*)&x4T[gbase + s0 + j*8] = *(const short8*)&trans[(lt << 9) + s0 + j*8];
  }
}

// K2: h = relu(x4 @ w) (in registers/LDS only); logits = h @ w1 via MFMA; CE/argmax/acc.
// Block 128 rows x 256 cols, 8 waves (2 row x 4 col).
__global__ __launch_bounds__(512) void k_gemm3_head(
    const unsigned short* __restrict__ x4T,
    const unsigned short* __restrict__ wT,
    const unsigned short* __restrict__ w1T,
    const int* __restrict__ y,
    float* __restrict__ scal)
{
  __shared__ __align__(16) char lds[49152];
  unsigned short* As     = (unsigned short*)lds;            // 16 x 1KB
  unsigned short* Bs     = (unsigned short*)(lds + 16384);  // 32 x 1KB
  unsigned short* transH = (unsigned short*)lds;            // epilogue: 32 x 1KB (h half, frag-tiled)
  __shared__ __align__(16) unsigned short w1s[4096];        // 8 x 1KB w1 B-tiles
  __shared__ float redc[8], reda[8];

  int blk = blockIdx.x;
  int t = threadIdx.x;
  int wv = t >> 6, lane = t & 63, ln = lane & 15, quad = lane >> 4;
  int wr = wv >> 2, wc = wv & 3;
  int rep = (blk ^ (blk >> 4)) & (NREP-1);

  *(short8*)&w1s[t*8] = *(const short8*)&w1T[t*8];

  const f32x4 zv = {0.f,0.f,0.f,0.f};
  f32x4 acc[4][4];
  #pragma unroll
  for (int rt=0;rt<4;++rt)
    #pragma unroll
    for (int ct=0;ct<4;++ct) acc[rt][ct] = zv;

  const char* ab = (const char*)x4T;
  const char* bb = (const char*)wT;

  for (int kt = 0; kt < 8; ++kt){
    {
      size_t Ig = (size_t)(blk*8 + wv);
      GLL(ab + ((Ig*16 + kt*2 + 0) << 10) + lane*16, (char*)As + ((wv*2+0) << 10));
      GLL(ab + ((Ig*16 + kt*2 + 1) << 10) + lane*16, (char*)As + ((wv*2+1) << 10));
    }
    #pragma unroll
    for (int i = 0; i < 2; ++i)
      #pragma unroll
      for (int c = 0; c < 2; ++c){
        size_t Jg = (size_t)(wv*2 + i);
        GLL(bb + ((Jg*16 + kt*2 + c) << 10) + lane*16,
            (char*)Bs + (((wv*2+i)*2 + c) << 10));
      }
    __syncthreads();
    #pragma unroll
    for (int c = 0; c < 2; ++c){
      short8 a[4];
      #pragma unroll
      for (int rt=0;rt<4;++rt)
        a[rt] = *(const short8*)&As[(((wr*4+rt)*2 + c) << 9) + lane*8];
      #pragma unroll
      for (int ct=0;ct<4;++ct){
        short8 b = *(const short8*)&Bs[(((wc*4+ct)*2 + c) << 9) + lane*8];
        #pragma unroll
        for (int rt=0;rt<4;++rt)
          acc[rt][ct] = __builtin_amdgcn_mfma_f32_16x16x32_bf16(a[rt], b, acc[rt][ct], 0,0,0);
      }
    }
    __syncthreads();
  }

  // epilogue: per 128-col half, write relu(h) fragment-tiled -> logits MFMA
  f32x4 alog = zv;
  #pragma unroll
  for (int hf = 0; hf < 2; ++hf){
    __syncthreads();
    if ((wc >> 1) == hf){
      #pragma unroll
      for (int rt=0;rt<4;++rt)
        #pragma unroll
        for (int ct=0;ct<4;++ct)
          #pragma unroll
          for (int r=0;r<4;++r){
            int row_l = wr*64 + rt*16 + quad*4 + r;
            int ch = (wc & 1)*64 + ct*16 + ln;     // col within half
            int tile = ((row_l >> 4) << 2) | (ch >> 5);
            int slot = (row_l & 15) | (((ch >> 3) & 3) << 4);
            transH[(tile << 9) + slot*8 + (ch & 7)] = f2b(fmaxf(acc[rt][ct][r], 0.f));
          }
    }
    __syncthreads();
    #pragma unroll
    for (int Cl = 0; Cl < 4; ++Cl){
      short8 a = *(const short8*)&transH[((wv*4 + Cl) << 9) + lane*8];
      short8 b = *(const short8*)&w1s[(hf*4 + Cl)*512 + lane*8];
      alog = __builtin_amdgcn_mfma_f32_16x16x32_bf16(a, b, alog, 0,0,0);
    }
  }

  // CE/argmax: logits for row (wv*16 + quad*4 + r), class = ln
  float ce_l = 0.f, acc_l = 0.f;
  #pragma unroll
  for (int r = 0; r < 4; ++r){
    int grow = blk*128 + wv*16 + quad*4 + r;
    int yv = y[grow];
    float lg = (ln < NC) ? alog[r] : -1e30f;
    float m = lg; int mi = ln;
    #pragma unroll
    for (int mk = 1; mk < 16; mk <<= 1){
      float om = __shfl_xor(m, mk); int oi = __shfl_xor(mi, mk);
      if (om > m || (om == m && oi < mi)){ m = om; mi = oi; }
    }
    float e  = (ln < NC) ? __expf(lg - m) : 0.f;
    float sy = (ln == yv) ? lg : 0.f;
    #pragma unroll
    for (int mk = 1; mk < 16; mk <<= 1){ e += __shfl_xor(e, mk); sy += __shfl_xor(sy, mk); }
    float lse = m + __logf(e);
    if (ln == 0){ ce_l += (lse - sy); acc_l += (mi == yv) ? 1.f : 0.f; }
  }
  ce_l  += __shfl_down(ce_l, 16);  acc_l += __shfl_down(acc_l, 16);
  ce_l  += __shfl_down(ce_l, 32);  acc_l += __shfl_down(acc_l, 32);
  if (lane == 0){ redc[wv] = ce_l; reda[wv] = acc_l; }
  __syncthreads();
  if (t == 0){
    float c = 0.f, a = 0.f;
    #pragma unroll
    for (int i=0;i<8;++i){ c += redc[i]; a += reda[i]; }
    atomicAdd(&scal[SCAL_CE  + rep], c);
    atomicAdd(&scal[SCAL_ACC + rep], a);
  }
}

// K3: reduce gsum/gcnt -> var term; finalize loss/acc. One block.
__global__ __launch_bounds__(1024) void k_final(const float* __restrict__ accb,
                                                float* __restrict__ out){
  const float* gsum = accb + GSUM_OFF;
  const float* gcnt = accb + CNT_OFF;
  int t = threadIdx.x;
  float contrib = 0.f;
  for (int idx = t; idx < 5120; idx += 1024){
    float S = 0.f;
    #pragma unroll
    for (int r = 0; r < NREP; ++r) S += gsum[(size_t)r*5120 + idx];
    int c = idx >> 9;
    float cnt = 0.f;
    #pragma unroll
    for (int r = 0; r < NREP; ++r) cnt += gcnt[r*16 + c];
    contrib += S*S / fmaxf(cnt, 1.f);
  }
  for (int off = 32; off; off >>= 1) contrib += __shfl_down(contrib, off);
  __shared__ float red[16];
  if ((t & 63) == 0) red[t >> 6] = contrib;
  __syncthreads();
  if (t == 0){
    float var2 = 0.f;
    #pragma unroll
    for (int i=0;i<16;++i) var2 += red[i];
    float sumsq=0.f, ce=0.f, acc=0.f, l1=0.f;
    for (int r=0;r<NREP;++r){
      sumsq += accb[SCAL_SUMSQ+r];
      ce    += accb[SCAL_CE+r];
      acc   += accb[SCAL_ACC+r];
      l1    += accb[SCAL_L1+r];
    }
    float var_loss = sumsq - var2;
    out[0] = ce/(float)BATCH + 1e-4f*l1 + 1e-3f*var_loss;
    out[1] = acc/(float)BATCH;
  }
}

extern "C" void kernel_launch(void* const* d_in, const int* in_sizes, int n_in,
                              void* d_out, int out_size, void* d_ws, size_t ws_size,
                              hipStream_t stream){
  (void)in_sizes; (void)n_in; (void)out_size; (void)ws_size;
  const float* x   = (const float*)d_in[0];
  const int*   y   = (const int*)d_in[1];
  const float* fc0 = (const float*)d_in[2];
  const float* fc1 = (const float*)d_in[3];
  const float* w   = (const float*)d_in[4];
  const float* w1  = (const float*)d_in[5];
  char* ws = (char*)d_ws;
  unsigned short* fc0T = (unsigned short*)(ws + OFF_FC0T);
  unsigned short* fc1T = (unsigned short*)(ws + OFF_FC1T);
  unsigned short* wT   = (unsigned short*)(ws + OFF_WT);
  unsigned short* xT   = (unsigned short*)(ws + OFF_XT);
  unsigned short* x4T  = (unsigned short*)(ws + OFF_X4T);
  unsigned short* w1T  = (unsigned short*)(ws + OFF_W1T);
  float* accb = (float*)(ws + OFF_ACC);
  float* scal = accb;
  float* gcnt = accb + CNT_OFF;
  float* gsum = accb + GSUM_OFF;

  k_setup<<<1441, 256, 0, stream>>>(x, fc0, fc1, w, w1, xT, fc0T, fc1T, wT, w1T, accb);
  k_gemm12<<<4096, 256, 0, stream>>>(xT, fc0T, fc1T, y, x4T, scal, gcnt, gsum);
  k_gemm3_head<<<512, 512, 0, stream>>>(x4T, wT, w1T, y, scal);
  k_final<<<1, 1024, 0, stream>>>(accb, (float*)d_out);
}

// Round 5
// 409.323 us; speedup vs baseline: 1.2600x; 1.2600x over previous
//
#include <hip/hip_runtime.h>
#include <stdint.h>

#define BATCH 65536
#define FDIM 512
#define HDIM 256
#define NC 10
#define NREP 16

typedef short short8 __attribute__((ext_vector_type(8)));
typedef float f32x4 __attribute__((ext_vector_type(4)));

// ---- workspace layout (bytes) ----
// Fragment-tiled layout: tile (I=row/16, C=k/32) is 1KB at (I*nC + C)*1024;
// slot l = (row&15) | (((k>>3)&3)<<4) holds 8 bf16 (k = (l>>4)*8 .. +7).
#define OFF_FC0T   ((size_t)0)                          // 32 J x 16 C tiles
#define OFF_FC1T   (OFF_FC0T + (size_t)512*512*2)
#define OFF_WT     (OFF_FC1T + (size_t)512*512*2)       // 16 J x 16 C tiles
#define OFF_XT     (OFF_WT   + (size_t)256*512*2)       // 4096 I x 16 C (64MB)
#define OFF_X4T    (OFF_XT   + (size_t)BATCH*512*2)     // 4096 I x 16 C (64MB)
#define OFF_ACC    (OFF_X4T  + (size_t)BATCH*512*2)
#define SCAL_SUMSQ 0
#define SCAL_CE    16
#define SCAL_ACC   32
#define SCAL_L1    48
#define SCAL_N     128
#define CNT_OFF    SCAL_N                 // NREP*16 floats
#define GSUM_OFF   (SCAL_N + NREP*16)     // NREP*5120 floats
#define ACC_FLOATS (GSUM_OFF + NREP*5120) // 82304 floats
#define OFF_W1T    (OFF_ACC + (size_t)ACC_FLOATS*4)     // 8 C-tiles x 1KB (w1 bf16, padded to 16 classes)

#define GLL(g,l) __builtin_amdgcn_global_load_lds((const __attribute__((address_space(1))) void*)(g), (__attribute__((address_space(3))) void*)(l), 16, 0, 0)

__device__ __forceinline__ unsigned short f2b(float f){
  unsigned u = __float_as_uint(f);
  u += 0x7FFFu + ((u >> 16) & 1u);
  return (unsigned short)(u >> 16);
}
__device__ __forceinline__ float b2f(unsigned short h){
  return __uint_as_float(((unsigned)h) << 16);
}
__device__ __forceinline__ unsigned pk2b(float f0, float f1){
  unsigned u0 = __float_as_uint(f0) + 0x8000u;
  unsigned u1 = __float_as_uint(f1) + 0x8000u;
  return __builtin_amdgcn_perm(u1, u0, 0x07060302u);
}

// ---- K0: setup — xcast (blocks 0..1023), weight prep (1024..1359), zero (1360..1440)
__global__ __launch_bounds__(256) void k_setup(
    const float* __restrict__ x,   const float* __restrict__ fc0,
    const float* __restrict__ fc1, const float* __restrict__ w,
    const float* __restrict__ w1,
    unsigned short* __restrict__ xT,   unsigned short* __restrict__ fc0T,
    unsigned short* __restrict__ fc1T, unsigned short* __restrict__ wT,
    unsigned short* __restrict__ w1T,  float* __restrict__ accb)
{
  int blk = blockIdx.x, t = threadIdx.x;
  if (blk < 1024){
    int I = blk*4 + (t >> 6);
    int l = t & 63;
    int row = I*16 + (l & 15), q = l >> 4;
    const float* src = x + (size_t)row*FDIM + q*8;
    #pragma unroll
    for (int C = 0; C < 16; ++C){
      float4 v0 = *(const float4*)(src + C*32);
      float4 v1 = *(const float4*)(src + C*32 + 4);
      unsigned o[4];
      o[0] = pk2b(v0.x, v0.y); o[1] = pk2b(v0.z, v0.w);
      o[2] = pk2b(v1.x, v1.y); o[3] = pk2b(v1.z, v1.w);
      *(short8*)&xT[(((size_t)I*16 + C) << 9) + l*8] = *(short8*)o;
    }
    return;
  }
  if (blk < 1360){
    int i = (blk - 1024)*256 + t;
    float l1v = 0.f;
    if (i < 32768){                       // fc0 [k][512] -> tiled
      int n4 = i&15, m = (i>>4)&3, C = (i>>6)&15, J = i>>10;
      int n = J*16+n4, k8 = C*4+m;
      unsigned short o[8];
      #pragma unroll
      for (int j=0;j<8;++j){ float v = fc0[(size_t)(k8*8+j)*512 + n]; o[j]=f2b(v); l1v += fabsf(v); }
      *(short8*)&fc0T[(size_t)(J*16+C)*512 + (i&63)*8] = *(short8*)o;
    } else if (i < 65536){                // fc1
      int j0 = i - 32768;
      int n4 = j0&15, m = (j0>>4)&3, C = (j0>>6)&15, J = j0>>10;
      int n = J*16+n4, k8 = C*4+m;
      unsigned short o[8];
      #pragma unroll
      for (int j=0;j<8;++j){ float v = fc1[(size_t)(k8*8+j)*512 + n]; o[j]=f2b(v); l1v += fabsf(v); }
      *(short8*)&fc1T[(size_t)(J*16+C)*512 + (j0&63)*8] = *(short8*)o;
    } else if (i < 81920){                // w [k][256]
      int j0 = i - 65536;
      int n4 = j0&15, m = (j0>>4)&3, C = (j0>>6)&15, J = j0>>10;
      int n = J*16+n4, k8 = C*4+m;
      unsigned short o[8];
      #pragma unroll
      for (int j=0;j<8;++j){ float v = w[(size_t)(k8*8+j)*256 + n]; o[j]=f2b(v); l1v += fabsf(v); }
      *(short8*)&wT[(size_t)(J*16+C)*512 + (j0&63)*8] = *(short8*)o;
    } else if (i < 86016){                // w1 -> B-fragment tiles (16 classes padded), + L1
      int j0 = i - 81920;                 // 0..4095, one bf16 each
      int C = j0 >> 9, l = (j0 >> 3) & 63, e = j0 & 7;
      int n = l & 15, k = C*32 + (l>>4)*8 + e;
      float v = (n < NC) ? w1[k*NC + n] : 0.f;
      w1T[C*512 + l*8 + e] = f2b(v);
      if (n < NC) l1v = fabsf(v);
    }
    for (int off = 32; off; off >>= 1) l1v += __shfl_down(l1v, off);
    if ((t & 63) == 0 && l1v != 0.f)
      atomicAdd(&accb[SCAL_L1 + (blk & (NREP-1))], l1v);
    return;
  }
  {
    int base = (blk - 1360)*1024;
    #pragma unroll
    for (int j=0;j<4;++j){
      int idx = base + j*256 + t;
      if (idx < ACC_FLOATS) accb[idx] = 0.f;
    }
  }
}

// K1: pure-GLL dual GEMM (R3-proven). Block = 128 rows x 64 cols; 4 waves (2r x 2c).
__global__ __launch_bounds__(256) void k_gemm12(
    const unsigned short* __restrict__ xT,
    const unsigned short* __restrict__ fc0T,
    const unsigned short* __restrict__ fc1T,
    unsigned short* __restrict__ x4T,
    float* __restrict__ scal)
{
  __shared__ __align__(16) char lds[32768];
  unsigned short* As    = (unsigned short*)lds;           // 16 x 1KB tiles
  unsigned short* Bs0   = (unsigned short*)(lds + 16384); // 8 x 1KB
  unsigned short* Bs1   = (unsigned short*)(lds + 24576); // 8 x 1KB
  unsigned short* trans = (unsigned short*)(lds + 16384); // epilogue reuse, 16KB
  __shared__ float red[4];

  int blk = blockIdx.x;
  int xcd = blk & 7, s = blk >> 3;
  int rowblk = xcd*64 + (s >> 3);
  int colblk = s & 7;

  int t = threadIdx.x;
  int wv = t >> 6, lane = t & 63, ln = lane & 15, quad = lane >> 4;
  int wr = wv >> 1, wc = wv & 1;

  const f32x4 zv = {0.f,0.f,0.f,0.f};
  f32x4 acc1[4][2], acc2[4][2];
  #pragma unroll
  for (int rt=0;rt<4;++rt){ acc1[rt][0]=zv; acc1[rt][1]=zv; acc2[rt][0]=zv; acc2[rt][1]=zv; }

  const char* xb  = (const char*)xT;
  const char* b0b = (const char*)fc0T;
  const char* b1b = (const char*)fc1T;

  for (int kt = 0; kt < 8; ++kt){
    #pragma unroll
    for (int i = 0; i < 2; ++i)
      #pragma unroll
      for (int c = 0; c < 2; ++c){
        size_t Ig = (size_t)(rowblk*8 + wv*2 + i);
        GLL(xb + ((Ig*16 + kt*2 + c) << 10) + lane*16,
            (char*)As + (((wv*2+i)*2 + c) << 10));
      }
    {
      size_t Jg = (size_t)(colblk*4 + wv);
      const char* g0 = b0b + ((Jg*16 + kt*2) << 10) + lane*16;
      const char* g1 = b1b + ((Jg*16 + kt*2) << 10) + lane*16;
      GLL(g0,        (char*)Bs0 + ((wv*2+0) << 10));
      GLL(g0 + 1024, (char*)Bs0 + ((wv*2+1) << 10));
      GLL(g1,        (char*)Bs1 + ((wv*2+0) << 10));
      GLL(g1 + 1024, (char*)Bs1 + ((wv*2+1) << 10));
    }
    __syncthreads();
    #pragma unroll
    for (int c = 0; c < 2; ++c){
      short8 a[4];
      #pragma unroll
      for (int rt=0;rt<4;++rt)
        a[rt] = *(const short8*)&As[(((wr*4+rt)*2 + c) << 9) + lane*8];
      #pragma unroll
      for (int ct=0;ct<2;++ct){
        int jl = wc*2 + ct;
        short8 b0 = *(const short8*)&Bs0[((jl*2+c) << 9) + lane*8];
        #pragma unroll
        for (int rt=0;rt<4;++rt)
          acc1[rt][ct] = __builtin_amdgcn_mfma_f32_16x16x32_bf16(a[rt], b0, acc1[rt][ct], 0,0,0);
        short8 b1 = *(const short8*)&Bs1[((jl*2+c) << 9) + lane*8];
        #pragma unroll
        for (int rt=0;rt<4;++rt)
          acc2[rt][ct] = __builtin_amdgcn_mfma_f32_16x16x32_bf16(a[rt], b1, acc2[rt][ct], 0,0,0);
      }
    }
    __syncthreads();
  }

  // re-stage this block's own column-slice of x for the residual (bf16)
  #pragma unroll
  for (int i = 0; i < 2; ++i)
    #pragma unroll
    for (int c = 0; c < 2; ++c){
      size_t Ig = (size_t)(rowblk*8 + wv*2 + i);
      GLL(xb + ((Ig*16 + colblk*2 + c) << 10) + lane*16,
          (char*)As + (((wv*2+i)*2 + c) << 10));
    }
  __syncthreads();

  float sumsq = 0.f;
  #pragma unroll
  for (int rt=0;rt<4;++rt){
    #pragma unroll
    for (int ct=0;ct<2;++ct){
      int slot_hi = (ct*2 + (ln>>3)) << 4;
      int elem = ln & 7;
      #pragma unroll
      for (int r=0;r<4;++r){
        int addr = (((wr*4+rt)*2 + wc) << 9) + ((quad*4+r) | slot_hi)*8 + elem;
        float xv  = b2f(As[addr]);
        float x1v = acc1[rt][ct][r];
        float x2v = fmaxf(acc2[rt][ct][r], 0.f);
        float gate = 1.f + 1.f/(1.f + __expf(-x1v));
        float x4v = fmaf(gate, x2v, xv);
        unsigned short ub = f2b(x4v);
        float fq = b2f(ub);
        sumsq = fmaf(fq, fq, sumsq);
        trans[addr] = ub;           // identical tiled position in x4
      }
    }
  }
  for (int off = 32; off; off >>= 1) sumsq += __shfl_down(sumsq, off);
  if (lane == 0) red[wv] = sumsq;
  __syncthreads();
  if (t == 0)
    atomicAdd(&scal[SCAL_SUMSQ + (blk & (NREP-1))], red[0]+red[1]+red[2]+red[3]);
  {
    int lt = t >> 4;                       // local tile 0..15
    int I_local = lt >> 1, C_local = lt & 1;
    size_t gbase = ((size_t)(rowblk*8 + I_local)*16 + colblk*2 + C_local) << 9;
    int s0 = (t & 15)*32;
    #pragma unroll
    for (int j=0;j<4;++j)
      *(short8*)&x4T[gbase + s0 + j*8] = *(const short8*)&trans[(lt << 9) + s0 + j*8];
  }
}

// class sums from tiled x4: one wave per (C-phase, 64 I-tiles) — R3-proven
__global__ __launch_bounds__(256) void k_csum(const unsigned short* __restrict__ x4T,
                                              const int* __restrict__ y,
                                              float* __restrict__ gsum){
  int w = blockIdx.x*4 + (threadIdx.x >> 6);   // 1024 waves
  int l = threadIdx.x & 63;
  int C = w & 15, Ig = w >> 4;                 // Ig 0..63
  int rl = l & 15, q = l >> 4;
  float a[NC][8];
  #pragma unroll
  for (int c=0;c<NC;++c)
    #pragma unroll
    for (int e=0;e<8;++e) a[c][e]=0.f;
  for (int ii = 0; ii < 64; ++ii){
    int I = Ig*64 + ii;
    int yv = y[I*16 + rl];
    short8 v = *(const short8*)&x4T[(((size_t)I*16 + C) << 9) + l*8];
    float f[8];
    #pragma unroll
    for (int e=0;e<8;++e) f[e] = b2f((unsigned short)v[e]);
    #pragma unroll
    for (int c=0;c<NC;++c){
      bool m = (yv == c);
      #pragma unroll
      for (int e=0;e<8;++e) a[c][e] += m ? f[e] : 0.f;
    }
  }
  #pragma unroll
  for (int off = 1; off < 16; off <<= 1)
    #pragma unroll
    for (int c=0;c<NC;++c)
      #pragma unroll
      for (int e=0;e<8;++e) a[c][e] += __shfl_xor(a[c][e], off);
  if (rl == 0){
    int rep = Ig & (NREP-1);
    int kb = C*32 + q*8;
    #pragma unroll
    for (int c=0;c<NC;++c)
      #pragma unroll
      for (int e=0;e<8;++e)
        atomicAdd(&gsum[(size_t)rep*5120 + c*512 + kb + e], a[c][e]);
  }
}

// counts of each class
__global__ __launch_bounds__(256) void k_cnt(const int* __restrict__ y,
                                             float* __restrict__ gcnt){
  __shared__ float cntS[NC];
  int t = threadIdx.x;
  if (t < NC) cntS[t] = 0.f;
  __syncthreads();
  int base = blockIdx.x*2048;
  for (int i = t; i < 2048; i += 256) atomicAdd(&cntS[y[base+i]], 1.f);
  __syncthreads();
  if (t < NC) atomicAdd(&gcnt[(blockIdx.x & (NREP-1))*16 + t], cntS[t]);
}

// K2: h = relu(x4 @ w) (LDS only); logits = h @ w1 via MFMA; CE/argmax/acc.
__global__ __launch_bounds__(512) void k_gemm3_head(
    const unsigned short* __restrict__ x4T,
    const unsigned short* __restrict__ wT,
    const unsigned short* __restrict__ w1T,
    const int* __restrict__ y,
    float* __restrict__ scal)
{
  __shared__ __align__(16) char lds[49152];
  unsigned short* As     = (unsigned short*)lds;            // 16 x 1KB
  unsigned short* Bs     = (unsigned short*)(lds + 16384);  // 32 x 1KB
  unsigned short* transH = (unsigned short*)lds;            // epilogue: 32 x 1KB (h half, frag-tiled)
  __shared__ __align__(16) unsigned short w1s[4096];        // 8 x 1KB w1 B-tiles
  __shared__ float redc[8], reda[8];

  int blk = blockIdx.x;
  int t = threadIdx.x;
  int wv = t >> 6, lane = t & 63, ln = lane & 15, quad = lane >> 4;
  int wr = wv >> 2, wc = wv & 3;
  int rep = (blk ^ (blk >> 4)) & (NREP-1);

  *(short8*)&w1s[t*8] = *(const short8*)&w1T[t*8];

  const f32x4 zv = {0.f,0.f,0.f,0.f};
  f32x4 acc[4][4];
  #pragma unroll
  for (int rt=0;rt<4;++rt)
    #pragma unroll
    for (int ct=0;ct<4;++ct) acc[rt][ct] = zv;

  const char* ab = (const char*)x4T;
  const char* bb = (const char*)wT;

  for (int kt = 0; kt < 8; ++kt){
    {
      size_t Ig = (size_t)(blk*8 + wv);
      GLL(ab + ((Ig*16 + kt*2 + 0) << 10) + lane*16, (char*)As + ((wv*2+0) << 10));
      GLL(ab + ((Ig*16 + kt*2 + 1) << 10) + lane*16, (char*)As + ((wv*2+1) << 10));
    }
    #pragma unroll
    for (int i = 0; i < 2; ++i)
      #pragma unroll
      for (int c = 0; c < 2; ++c){
        size_t Jg = (size_t)(wv*2 + i);
        GLL(bb + ((Jg*16 + kt*2 + c) << 10) + lane*16,
            (char*)Bs + (((wv*2+i)*2 + c) << 10));
      }
    __syncthreads();
    #pragma unroll
    for (int c = 0; c < 2; ++c){
      short8 a[4];
      #pragma unroll
      for (int rt=0;rt<4;++rt)
        a[rt] = *(const short8*)&As[(((wr*4+rt)*2 + c) << 9) + lane*8];
      #pragma unroll
      for (int ct=0;ct<4;++ct){
        short8 b = *(const short8*)&Bs[(((wc*4+ct)*2 + c) << 9) + lane*8];
        #pragma unroll
        for (int rt=0;rt<4;++rt)
          acc[rt][ct] = __builtin_amdgcn_mfma_f32_16x16x32_bf16(a[rt], b, acc[rt][ct], 0,0,0);
      }
    }
    __syncthreads();
  }

  // epilogue: per 128-col half, write relu(h) fragment-tiled -> logits MFMA
  f32x4 alog = zv;
  #pragma unroll
  for (int hf = 0; hf < 2; ++hf){
    __syncthreads();
    if ((wc >> 1) == hf){
      #pragma unroll
      for (int rt=0;rt<4;++rt)
        #pragma unroll
        for (int ct=0;ct<4;++ct)
          #pragma unroll
          for (int r=0;r<4;++r){
            int row_l = wr*64 + rt*16 + quad*4 + r;
            int ch = (wc & 1)*64 + ct*16 + ln;
            int tile = ((row_l >> 4) << 2) | (ch >> 5);
            int slot = (row_l & 15) | (((ch >> 3) & 3) << 4);
            transH[(tile << 9) + slot*8 + (ch & 7)] = f2b(fmaxf(acc[rt][ct][r], 0.f));
          }
    }
    __syncthreads();
    #pragma unroll
    for (int Cl = 0; Cl < 4; ++Cl){
      short8 a = *(const short8*)&transH[((wv*4 + Cl) << 9) + lane*8];
      short8 b = *(const short8*)&w1s[(hf*4 + Cl)*512 + lane*8];
      alog = __builtin_amdgcn_mfma_f32_16x16x32_bf16(a, b, alog, 0,0,0);
    }
  }

  // CE/argmax: logits for row (wv*16 + quad*4 + r), class = ln
  float ce_l = 0.f, acc_l = 0.f;
  #pragma unroll
  for (int r = 0; r < 4; ++r){
    int grow = blk*128 + wv*16 + quad*4 + r;
    int yv = y[grow];
    float lg = (ln < NC) ? alog[r] : -1e30f;
    float m = lg; int mi = ln;
    #pragma unroll
    for (int mk = 1; mk < 16; mk <<= 1){
      float om = __shfl_xor(m, mk); int oi = __shfl_xor(mi, mk);
      if (om > m || (om == m && oi < mi)){ m = om; mi = oi; }
    }
    float e  = (ln < NC) ? __expf(lg - m) : 0.f;
    float sy = (ln == yv) ? lg : 0.f;
    #pragma unroll
    for (int mk = 1; mk < 16; mk <<= 1){ e += __shfl_xor(e, mk); sy += __shfl_xor(sy, mk); }
    float lse = m + __logf(e);
    if (ln == 0){ ce_l += (lse - sy); acc_l += (mi == yv) ? 1.f : 0.f; }
  }
  ce_l  += __shfl_down(ce_l, 16);  acc_l += __shfl_down(acc_l, 16);
  ce_l  += __shfl_down(ce_l, 32);  acc_l += __shfl_down(acc_l, 32);
  if (lane == 0){ redc[wv] = ce_l; reda[wv] = acc_l; }
  __syncthreads();
  if (t == 0){
    float c = 0.f, a = 0.f;
    #pragma unroll
    for (int i=0;i<8;++i){ c += redc[i]; a += reda[i]; }
    atomicAdd(&scal[SCAL_CE  + rep], c);
    atomicAdd(&scal[SCAL_ACC + rep], a);
  }
}

// K3: reduce gsum/gcnt -> var term; finalize loss/acc. One block.
__global__ __launch_bounds__(1024) void k_final(const float* __restrict__ accb,
                                                float* __restrict__ out){
  const float* gsum = accb + GSUM_OFF;
  const float* gcnt = accb + CNT_OFF;
  int t = threadIdx.x;
  float contrib = 0.f;
  for (int idx = t; idx < 5120; idx += 1024){
    float S = 0.f;
    #pragma unroll
    for (int r = 0; r < NREP; ++r) S += gsum[(size_t)r*5120 + idx];
    int c = idx >> 9;
    float cnt = 0.f;
    #pragma unroll
    for (int r = 0; r < NREP; ++r) cnt += gcnt[r*16 + c];
    contrib += S*S / fmaxf(cnt, 1.f);
  }
  for (int off = 32; off; off >>= 1) contrib += __shfl_down(contrib, off);
  __shared__ float red[16];
  if ((t & 63) == 0) red[t >> 6] = contrib;
  __syncthreads();
  if (t == 0){
    float var2 = 0.f;
    #pragma unroll
    for (int i=0;i<16;++i) var2 += red[i];
    float sumsq=0.f, ce=0.f, acc=0.f, l1=0.f;
    for (int r=0;r<NREP;++r){
      sumsq += accb[SCAL_SUMSQ+r];
      ce    += accb[SCAL_CE+r];
      acc   += accb[SCAL_ACC+r];
      l1    += accb[SCAL_L1+r];
    }
    float var_loss = sumsq - var2;
    out[0] = ce/(float)BATCH + 1e-4f*l1 + 1e-3f*var_loss;
    out[1] = acc/(float)BATCH;
  }
}

extern "C" void kernel_launch(void* const* d_in, const int* in_sizes, int n_in,
                              void* d_out, int out_size, void* d_ws, size_t ws_size,
                              hipStream_t stream){
  (void)in_sizes; (void)n_in; (void)out_size; (void)ws_size;
  const float* x   = (const float*)d_in[0];
  const int*   y   = (const int*)d_in[1];
  const float* fc0 = (const float*)d_in[2];
  const float* fc1 = (const float*)d_in[3];
  const float* w   = (const float*)d_in[4];
  const float* w1  = (const float*)d_in[5];
  char* ws = (char*)d_ws;
  unsigned short* fc0T = (unsigned short*)(ws + OFF_FC0T);
  unsigned short* fc1T = (unsigned short*)(ws + OFF_FC1T);
  unsigned short* wT   = (unsigned short*)(ws + OFF_WT);
  unsigned short* xT   = (unsigned short*)(ws + OFF_XT);
  unsigned short* x4T  = (unsigned short*)(ws + OFF_X4T);
  unsigned short* w1T  = (unsigned short*)(ws + OFF_W1T);
  float* accb = (float*)(ws + OFF_ACC);
  float* scal = accb;
  float* gcnt = accb + CNT_OFF;
  float* gsum = accb + GSUM_OFF;

  k_setup<<<1441, 256, 0, stream>>>(x, fc0, fc1, w, w1, xT, fc0T, fc1T, wT, w1T, accb);
  k_gemm12<<<4096, 256, 0, stream>>>(xT, fc0T, fc1T, x4T, scal);
  k_cnt<<<32, 256, 0, stream>>>(y, gcnt);
  k_csum<<<256, 256, 0, stream>>>(x4T, y, gsum);
  k_gemm3_head<<<512, 512, 0, stream>>>(x4T, wT, w1T, y, scal);
  k_final<<<1, 1024, 0, stream>>>(accb, (float*)d_out);
}